// Round 1
// baseline (445.214 us; speedup 1.0000x reference)
//
#include <hip/hip_runtime.h>
#include <hip/hip_bf16.h>
#include <stdint.h>

#define DIM_ 1024
#define NH_ 16
#define HD_ 64
#define B_ 4
#define S_ 2048
#define SC_ 1024
#define CD_ 768

typedef __attribute__((ext_vector_type(8))) short bf16x8;
typedef __attribute__((ext_vector_type(4))) float f32x4;

__device__ inline unsigned short f2bf(float f) {
    unsigned int u = __builtin_bit_cast(unsigned int, f);
    unsigned int r = (u + 0x7FFFu + ((u >> 16) & 1u)) >> 16;
    return (unsigned short)r;
}

// ---------------- conversion kernels ----------------
__global__ void k_f32_to_bf16(const float* __restrict__ in, unsigned short* __restrict__ out, int n4) {
    int i = blockIdx.x * blockDim.x + threadIdx.x;
    int stride = gridDim.x * blockDim.x;
    for (; i < n4; i += stride) {
        float4 v = ((const float4*)in)[i];
        uint2 pk;
        pk.x = (unsigned int)f2bf(v.x) | ((unsigned int)f2bf(v.y) << 16);
        pk.y = (unsigned int)f2bf(v.z) | ((unsigned int)f2bf(v.w) << 16);
        ((uint2*)out)[i] = pk;
    }
}

// W is (K x 1024), write WT (1024 x K) in bf16
__global__ void k_transposeW(const float* __restrict__ W, unsigned short* __restrict__ WT, int K) {
    int idx = blockIdx.x * blockDim.x + threadIdx.x;
    int total = K * 1024;
    int stride = gridDim.x * blockDim.x;
    for (; idx < total; idx += stride) {
        int k = idx >> 10, n = idx & 1023;
        WT[n * K + k] = f2bf(W[idx]);
    }
}

// detect whether mask buffer is byte-packed bool (flag=1) or int32 (flag=0)
__global__ void k_mask_probe(const unsigned int* __restrict__ m, int* __restrict__ flag) {
    __shared__ int s;
    if (threadIdx.x == 0) s = 0;
    __syncthreads();
    int any = 0;
    for (int i = threadIdx.x; i < 1024; i += 256) {  // first 4096 bytes: safe under both dtypes
        if (m[i] > 1u) any = 1;
    }
    if (any) atomicOr(&s, 1);
    __syncthreads();
    if (threadIdx.x == 0) *flag = s;
}

// ---------------- bf16 GEMM, B^T layout ----------------
// C(MxN) = A(MxK) * BT(NxK)^T + bias
// EPI 0: bf16 row-major out; EPI 1: bf16 V^T out (b, n, c) with m=b*1024+c; EPI 2: f32 row-major out
template<int EPI>
__global__ __launch_bounds__(256) void k_gemm_bt(
    const unsigned short* __restrict__ A, const unsigned short* __restrict__ BT,
    const float* __restrict__ bias, unsigned short* __restrict__ Cb, float* __restrict__ Cf,
    int M, int N, int K)
{
    __shared__ unsigned short As[128 * 40];  // +8 pad per row: breaks 64B-stride bank conflicts
    __shared__ unsigned short Bs[128 * 40];
    const int t = threadIdx.x;
    const int w = t >> 6, lane = t & 63;
    const int lo = lane & 15, hi = lane >> 4;
    const int m0 = blockIdx.x * 128, n0 = blockIdx.y * 128;
    const int wr = (w >> 1) * 64, wc = (w & 1) * 64;

    f32x4 zero4 = {0.f, 0.f, 0.f, 0.f};
    f32x4 acc[4][4];
    for (int i = 0; i < 4; ++i)
        for (int j = 0; j < 4; ++j) acc[i][j] = zero4;

    for (int k0 = 0; k0 < K; k0 += 32) {
        __syncthreads();
        for (int c = t; c < 512; c += 256) {
            int row = c >> 2, cg = (c & 3) << 3;
            *(bf16x8*)&As[row * 40 + cg] = *(const bf16x8*)&A[(size_t)(m0 + row) * K + k0 + cg];
            *(bf16x8*)&Bs[row * 40 + cg] = *(const bf16x8*)&BT[(size_t)(n0 + row) * K + k0 + cg];
        }
        __syncthreads();
        bf16x8 af[4], bfr[4];
#pragma unroll
        for (int i = 0; i < 4; ++i)
            af[i] = *(const bf16x8*)&As[(wr + i * 16 + lo) * 40 + (hi << 3)];
#pragma unroll
        for (int j = 0; j < 4; ++j)
            bfr[j] = *(const bf16x8*)&Bs[(wc + j * 16 + lo) * 40 + (hi << 3)];
#pragma unroll
        for (int i = 0; i < 4; ++i)
#pragma unroll
            for (int j = 0; j < 4; ++j)
                acc[i][j] = __builtin_amdgcn_mfma_f32_16x16x32_bf16(af[i], bfr[j], acc[i][j], 0, 0, 0);
    }

#pragma unroll
    for (int i = 0; i < 4; ++i) {
#pragma unroll
        for (int j = 0; j < 4; ++j) {
#pragma unroll
            for (int r = 0; r < 4; ++r) {
                int m = m0 + wr + i * 16 + (hi << 2) + r;
                int n = n0 + wc + j * 16 + lo;
                float v = acc[i][j][r] + bias[n];
                if (EPI == 0) {
                    Cb[(size_t)m * N + n] = f2bf(v);
                } else if (EPI == 1) {
                    int b = m >> 10, c = m & 1023;
                    Cb[(size_t)((b << 10) + n) * 1024 + c] = f2bf(v);
                } else {
                    Cf[(size_t)m * N + n] = v;
                }
            }
        }
    }
}

// ---------------- fused flash attention ----------------
// grid (S/64, NH, B), 256 threads. Each wave: 16 q-rows. KV tile = 64.
__global__ __launch_bounds__(256) void k_attn(
    const unsigned short* __restrict__ Q, const unsigned short* __restrict__ Kb,
    const unsigned short* __restrict__ VT, const void* __restrict__ maskp,
    const int* __restrict__ flagp, unsigned short* __restrict__ Ob)
{
    __shared__ unsigned short P[4][16][72];  // per-wave P tile, padded (+8) rows
    const int t = threadIdx.x, w = t >> 6, lane = t & 63;
    const int lo = lane & 15, hi = lane >> 4;
    const int qt = blockIdx.x, h = blockIdx.y, b = blockIdx.z;
    const int qr0 = qt * 64 + w * 16;
    const int boolmode = *flagp;
    const unsigned char* mb = (const unsigned char*)maskp;
    const int* mi = (const int*)maskp;

    bf16x8 qf[2];
#pragma unroll
    for (int kk = 0; kk < 2; ++kk)
        qf[kk] = *(const bf16x8*)&Q[(size_t)(b * S_ + qr0 + lo) * DIM_ + h * 64 + kk * 32 + hi * 8];

    f32x4 zero4 = {0.f, 0.f, 0.f, 0.f};
    float mrow[4], lsum[4];
    f32x4 o[4];
#pragma unroll
    for (int r = 0; r < 4; ++r) { mrow[r] = -1e30f; lsum[r] = 0.f; }
#pragma unroll
    for (int n = 0; n < 4; ++n) o[n] = zero4;

    for (int c0 = 0; c0 < SC_; c0 += 64) {
        f32x4 s[4];
#pragma unroll
        for (int n = 0; n < 4; ++n) s[n] = zero4;
#pragma unroll
        for (int n = 0; n < 4; ++n) {
#pragma unroll
            for (int kk = 0; kk < 2; ++kk) {
                bf16x8 kf = *(const bf16x8*)&Kb[(size_t)(b * SC_ + c0 + n * 16 + lo) * DIM_ + h * 64 + kk * 32 + hi * 8];
                s[n] = __builtin_amdgcn_mfma_f32_16x16x32_bf16(qf[kk], kf, s[n], 0, 0, 0);
            }
        }
        // scale + mask
        float sv[4][4];
#pragma unroll
        for (int n = 0; n < 4; ++n) {
            int c = c0 + n * 16 + lo;
            bool mk = boolmode ? (mb[b * SC_ + c] != 0) : (mi[b * SC_ + c] != 0);
#pragma unroll
            for (int r = 0; r < 4; ++r)
                sv[n][r] = mk ? -1e30f : s[n][r] * 0.125f;
        }
        // online softmax: row r lives in the 16 lanes of group hi at reg r
        float mnew[4], scl[4];
#pragma unroll
        for (int r = 0; r < 4; ++r) {
            float mx = fmaxf(fmaxf(sv[0][r], sv[1][r]), fmaxf(sv[2][r], sv[3][r]));
            mx = fmaxf(mx, __shfl_xor(mx, 1));
            mx = fmaxf(mx, __shfl_xor(mx, 2));
            mx = fmaxf(mx, __shfl_xor(mx, 4));
            mx = fmaxf(mx, __shfl_xor(mx, 8));
            mnew[r] = fmaxf(mrow[r], mx);
            scl[r] = __expf(mrow[r] - mnew[r]);
            mrow[r] = mnew[r];
        }
        __syncthreads();  // previous iteration's P reads complete before overwrite
        float rsum[4];
#pragma unroll
        for (int r = 0; r < 4; ++r) rsum[r] = 0.f;
#pragma unroll
        for (int n = 0; n < 4; ++n) {
#pragma unroll
            for (int r = 0; r < 4; ++r) {
                float p = __expf(sv[n][r] - mnew[r]);
                rsum[r] += p;
                P[w][hi * 4 + r][n * 16 + lo] = f2bf(p);
            }
        }
#pragma unroll
        for (int r = 0; r < 4; ++r) {
            float su = rsum[r];
            su += __shfl_xor(su, 1);
            su += __shfl_xor(su, 2);
            su += __shfl_xor(su, 4);
            su += __shfl_xor(su, 8);
            lsum[r] = lsum[r] * scl[r] + su;
        }
#pragma unroll
        for (int n = 0; n < 4; ++n)
#pragma unroll
            for (int r = 0; r < 4; ++r)
                o[n][r] *= scl[r];
        __syncthreads();  // P writes visible (cross-lane within wave)
        // PV: out(16q x 64d) += P(16 x 64) * V(64 x 64); B-operand = V^T rows
#pragma unroll
        for (int kk = 0; kk < 2; ++kk) {
            bf16x8 pf = *(const bf16x8*)&P[w][lo][kk * 32 + hi * 8];
#pragma unroll
            for (int n = 0; n < 4; ++n) {
                bf16x8 vf = *(const bf16x8*)&VT[(size_t)(b * DIM_ + h * 64 + n * 16 + lo) * SC_ + c0 + kk * 32 + hi * 8];
                o[n] = __builtin_amdgcn_mfma_f32_16x16x32_bf16(pf, vf, o[n], 0, 0, 0);
            }
        }
    }
    // epilogue: write bf16 attention output (b, s, h*64+d)
#pragma unroll
    for (int n = 0; n < 4; ++n) {
#pragma unroll
        for (int r = 0; r < 4; ++r) {
            int m = qr0 + hi * 4 + r;
            int d = n * 16 + lo;
            Ob[(size_t)(b * S_ + m) * DIM_ + h * 64 + d] = f2bf(o[n][r] / lsum[r]);
        }
    }
}

// ---------------- launch ----------------
extern "C" void kernel_launch(void* const* d_in, const int* in_sizes, int n_in,
                              void* d_out, int out_size, void* d_ws, size_t ws_size,
                              hipStream_t stream)
{
    const float* x  = (const float*)d_in[0];
    const float* cx = (const float*)d_in[1];
    const void* mask = d_in[2];
    const float* Wq = (const float*)d_in[3];
    const float* bq = (const float*)d_in[4];
    const float* Wk = (const float*)d_in[5];
    const float* bk = (const float*)d_in[6];
    const float* Wv = (const float*)d_in[7];
    const float* bv = (const float*)d_in[8];
    const float* Wo = (const float*)d_in[9];
    const float* bo = (const float*)d_in[10];

    unsigned short* ws = (unsigned short*)d_ws;
    // layout (ushort elements); xb is reused as attention output buffer
    const size_t XB  = 0;                                  // 8192*1024
    const size_t CXB = XB  + (size_t)8192 * 1024;          // 4096*768
    const size_t WQT = CXB + (size_t)4096 * 768;           // 1024*1024
    const size_t WKT = WQT + (size_t)1024 * 1024;          // 1024*768
    const size_t WVT = WKT + (size_t)1024 * 768;           // 1024*768
    const size_t WOT = WVT + (size_t)1024 * 768;           // 1024*1024
    const size_t QB  = WOT + (size_t)1024 * 1024;          // 8192*1024
    const size_t KB  = QB  + (size_t)8192 * 1024;          // 4096*1024
    const size_t VTB = KB  + (size_t)4096 * 1024;          // 4*1024*1024
    const size_t FLG = VTB + (size_t)4 * 1024 * 1024;      // 2 ushorts (one int)

    k_f32_to_bf16<<<2048, 256, 0, stream>>>(x,  ws + XB,  8192 * 1024 / 4);
    k_f32_to_bf16<<<2048, 256, 0, stream>>>(cx, ws + CXB, 4096 * 768 / 4);
    k_transposeW<<<1024, 256, 0, stream>>>(Wq, ws + WQT, 1024);
    k_transposeW<<<768,  256, 0, stream>>>(Wk, ws + WKT, 768);
    k_transposeW<<<768,  256, 0, stream>>>(Wv, ws + WVT, 768);
    k_transposeW<<<1024, 256, 0, stream>>>(Wo, ws + WOT, 1024);
    int* flag = (int*)(ws + FLG);
    k_mask_probe<<<1, 256, 0, stream>>>((const unsigned int*)mask, flag);

    dim3 gq(8192 / 128, 1024 / 128);
    dim3 gk(4096 / 128, 1024 / 128);
    // Q = x*Wq + bq  -> bf16 (B*S, DIM)
    k_gemm_bt<0><<<gq, 256, 0, stream>>>(ws + XB,  ws + WQT, bq, ws + QB, nullptr, 8192, 1024, 1024);
    // K = cx*Wk + bk -> bf16 (B*SC, DIM)
    k_gemm_bt<0><<<gk, 256, 0, stream>>>(ws + CXB, ws + WKT, bk, ws + KB, nullptr, 4096, 1024, 768);
    // V^T = (cx*Wv + bv)^T per batch -> bf16 (B, DIM, SC)
    k_gemm_bt<1><<<gk, 256, 0, stream>>>(ws + CXB, ws + WVT, bv, ws + VTB, nullptr, 4096, 1024, 768);

    dim3 ga(S_ / 64, NH_, B_);
    k_attn<<<ga, 256, 0, stream>>>(ws + QB, ws + KB, ws + VTB, mask, flag, ws + XB);

    // out = attn_out * Wo + bo -> f32 d_out
    k_gemm_bt<2><<<gq, 256, 0, stream>>>(ws + XB, ws + WOT, bo, nullptr, (float*)d_out, 8192, 1024, 1024);
}

// Round 2
// 423.319 us; speedup vs baseline: 1.0517x; 1.0517x over previous
//
#include <hip/hip_runtime.h>
#include <hip/hip_bf16.h>
#include <stdint.h>

#define DIM_ 1024
#define NH_ 16
#define HD_ 64
#define B_ 4
#define S_ 2048
#define SC_ 1024
#define CD_ 768

typedef __attribute__((ext_vector_type(8))) short bf16x8;
typedef __attribute__((ext_vector_type(4))) float f32x4;

__device__ inline unsigned short f2bf(float f) {
    unsigned int u = __builtin_bit_cast(unsigned int, f);
    unsigned int r = (u + 0x7FFFu + ((u >> 16) & 1u)) >> 16;
    return (unsigned short)r;
}

// ---------------- conversion kernels ----------------
__global__ void k_f32_to_bf16(const float* __restrict__ in, unsigned short* __restrict__ out, int n4) {
    int i = blockIdx.x * blockDim.x + threadIdx.x;
    int stride = gridDim.x * blockDim.x;
    for (; i < n4; i += stride) {
        float4 v = ((const float4*)in)[i];
        uint2 pk;
        pk.x = (unsigned int)f2bf(v.x) | ((unsigned int)f2bf(v.y) << 16);
        pk.y = (unsigned int)f2bf(v.z) | ((unsigned int)f2bf(v.w) << 16);
        ((uint2*)out)[i] = pk;
    }
}

// W is (K x 1024), write WT (1024 x K) in bf16
__global__ void k_transposeW(const float* __restrict__ W, unsigned short* __restrict__ WT, int K) {
    int idx = blockIdx.x * blockDim.x + threadIdx.x;
    int total = K * 1024;
    int stride = gridDim.x * blockDim.x;
    for (; idx < total; idx += stride) {
        int k = idx >> 10, n = idx & 1023;
        WT[n * K + k] = f2bf(W[idx]);
    }
}

// detect whether mask buffer is byte-packed bool (flag=1) or int32 (flag=0)
__global__ void k_mask_probe(const unsigned int* __restrict__ m, int* __restrict__ flag) {
    __shared__ int s;
    if (threadIdx.x == 0) s = 0;
    __syncthreads();
    int any = 0;
    for (int i = threadIdx.x; i < 1024; i += 256) {
        if (m[i] > 1u) any = 1;
    }
    if (any) atomicOr(&s, 1);
    __syncthreads();
    if (threadIdx.x == 0) *flag = s;
}

// ---------------- bf16 GEMM, B^T layout, global_load_lds staging (m97 pattern) ----------------
// C(MxN) = A(MxK) * BT(NxK)^T + bias
// EPI 0: bf16 row-major out; EPI 1: bf16 V^T out (b, n, c) with m=b*1024+c; EPI 2: f32 row-major out
template<int EPI>
__global__ __launch_bounds__(256) void k_gemm_bt(
    const unsigned short* __restrict__ A, const unsigned short* __restrict__ BT,
    const float* __restrict__ bias, unsigned short* __restrict__ Cb, float* __restrict__ Cf,
    int M, int N, int K)
{
    __shared__ unsigned short As[128 * 32];  // linear: global_load_lds dest must be contiguous
    __shared__ unsigned short Bs[128 * 32];
    const int t = threadIdx.x;
    const int w = t >> 6, lane = t & 63;
    const int lo = lane & 15, hi = lane >> 4;
    const int m0 = blockIdx.x * 128, n0 = blockIdx.y * 128;
    const int wr = (w >> 1) * 64, wc = (w & 1) * 64;
    // staging: wave w, pass p covers LDS chunk (w*2+p)*1024B; lane l -> row (chunk*16 + l/4), col (l%4)*8
    const int srow = lane >> 2;
    const int scol = (lane & 3) * 8;

    f32x4 zero4 = {0.f, 0.f, 0.f, 0.f};
    f32x4 acc[4][4];
    for (int i = 0; i < 4; ++i)
        for (int j = 0; j < 4; ++j) acc[i][j] = zero4;

    for (int k0 = 0; k0 < K; k0 += 32) {
#pragma unroll
        for (int p = 0; p < 2; ++p) {
            int chunk = w * 2 + p;
            int r = chunk * 16 + srow;
            __builtin_amdgcn_global_load_lds(
                (const __attribute__((address_space(1))) void*)&A[(size_t)(m0 + r) * K + k0 + scol],
                (__attribute__((address_space(3))) void*)&As[chunk * 512], 16, 0, 0);
            __builtin_amdgcn_global_load_lds(
                (const __attribute__((address_space(1))) void*)&BT[(size_t)(n0 + r) * K + k0 + scol],
                (__attribute__((address_space(3))) void*)&Bs[chunk * 512], 16, 0, 0);
        }
        __syncthreads();  // compiler drains vmcnt before barrier -> staged data visible
        bf16x8 af[4], bfr[4];
#pragma unroll
        for (int i = 0; i < 4; ++i)
            af[i] = *(const bf16x8*)&As[(wr + i * 16 + lo) * 32 + (hi << 3)];
#pragma unroll
        for (int j = 0; j < 4; ++j)
            bfr[j] = *(const bf16x8*)&Bs[(wc + j * 16 + lo) * 32 + (hi << 3)];
#pragma unroll
        for (int i = 0; i < 4; ++i)
#pragma unroll
            for (int j = 0; j < 4; ++j)
                acc[i][j] = __builtin_amdgcn_mfma_f32_16x16x32_bf16(af[i], bfr[j], acc[i][j], 0, 0, 0);
        __syncthreads();  // reads done before next stage overwrites
    }

#pragma unroll
    for (int i = 0; i < 4; ++i) {
#pragma unroll
        for (int j = 0; j < 4; ++j) {
#pragma unroll
            for (int r = 0; r < 4; ++r) {
                int m = m0 + wr + i * 16 + (hi << 2) + r;
                int n = n0 + wc + j * 16 + lo;
                float v = acc[i][j][r] + bias[n];
                if (EPI == 0) {
                    Cb[(size_t)m * N + n] = f2bf(v);
                } else if (EPI == 1) {
                    int b = m >> 10, c = m & 1023;
                    Cb[(size_t)((b << 10) + n) * 1024 + c] = f2bf(v);
                } else {
                    Cf[(size_t)m * N + n] = v;
                }
            }
        }
    }
}

// ---------------- fused flash attention (barrier-free, loads-at-top) ----------------
// grid (S/64, NH, B), 256 threads. Each wave: 16 q-rows, wave-private P bounce. KV tile = 64.
__global__ __launch_bounds__(256) void k_attn(
    const unsigned short* __restrict__ Q, const unsigned short* __restrict__ Kb,
    const unsigned short* __restrict__ VT, const void* __restrict__ maskp,
    const int* __restrict__ flagp, unsigned short* __restrict__ Ob)
{
    __shared__ unsigned short P[4][16][72];  // [wave][row][col+pad] -- strictly wave-private
    const int t = threadIdx.x, w = t >> 6, lane = t & 63;
    const int lo = lane & 15, hi = lane >> 4;
    const int qt = blockIdx.x, h = blockIdx.y, b = blockIdx.z;
    const int qr0 = qt * 64 + w * 16;
    const int boolmode = *flagp;
    const unsigned char* mb = (const unsigned char*)maskp;
    const int* mi = (const int*)maskp;

    bf16x8 qf[2];
#pragma unroll
    for (int kk = 0; kk < 2; ++kk)
        qf[kk] = *(const bf16x8*)&Q[(size_t)(b * S_ + qr0 + lo) * DIM_ + h * 64 + kk * 32 + hi * 8];

    f32x4 zero4 = {0.f, 0.f, 0.f, 0.f};
    float mrow[4], lsum[4];
    f32x4 o[4];
#pragma unroll
    for (int r = 0; r < 4; ++r) { mrow[r] = -1e30f; lsum[r] = 0.f; }
#pragma unroll
    for (int n = 0; n < 4; ++n) o[n] = zero4;

    for (int c0 = 0; c0 < SC_; c0 += 64) {
        // issue ALL K and V loads first: L2 latency hides under QK^T + softmax
        bf16x8 kf[4][2], vf[4][2];
#pragma unroll
        for (int n = 0; n < 4; ++n)
#pragma unroll
            for (int kk = 0; kk < 2; ++kk)
                kf[n][kk] = *(const bf16x8*)&Kb[(size_t)(b * SC_ + c0 + n * 16 + lo) * DIM_ + h * 64 + kk * 32 + hi * 8];
#pragma unroll
        for (int n = 0; n < 4; ++n)
#pragma unroll
            for (int kk = 0; kk < 2; ++kk)
                vf[n][kk] = *(const bf16x8*)&VT[(size_t)(b * DIM_ + h * 64 + n * 16 + lo) * SC_ + c0 + kk * 32 + hi * 8];

        f32x4 s[4];
#pragma unroll
        for (int n = 0; n < 4; ++n) s[n] = zero4;
#pragma unroll
        for (int n = 0; n < 4; ++n)
#pragma unroll
            for (int kk = 0; kk < 2; ++kk)
                s[n] = __builtin_amdgcn_mfma_f32_16x16x32_bf16(qf[kk], kf[n][kk], s[n], 0, 0, 0);

        // scale + mask
        float sv[4][4];
#pragma unroll
        for (int n = 0; n < 4; ++n) {
            int c = c0 + n * 16 + lo;
            bool mk = boolmode ? (mb[b * SC_ + c] != 0) : (mi[b * SC_ + c] != 0);
#pragma unroll
            for (int r = 0; r < 4; ++r)
                sv[n][r] = mk ? -1e30f : s[n][r] * 0.125f;
        }
        // online softmax: row r of this 4-row group lives in 16 lanes (group hi)
        float mnew[4], scl[4];
#pragma unroll
        for (int r = 0; r < 4; ++r) {
            float mx = fmaxf(fmaxf(sv[0][r], sv[1][r]), fmaxf(sv[2][r], sv[3][r]));
            mx = fmaxf(mx, __shfl_xor(mx, 1));
            mx = fmaxf(mx, __shfl_xor(mx, 2));
            mx = fmaxf(mx, __shfl_xor(mx, 4));
            mx = fmaxf(mx, __shfl_xor(mx, 8));
            mnew[r] = fmaxf(mrow[r], mx);
            scl[r] = __expf(mrow[r] - mnew[r]);
            mrow[r] = mnew[r];
        }
        float rsum[4];
#pragma unroll
        for (int r = 0; r < 4; ++r) rsum[r] = 0.f;
#pragma unroll
        for (int n = 0; n < 4; ++n) {
#pragma unroll
            for (int r = 0; r < 4; ++r) {
                float p = __expf(sv[n][r] - mnew[r]);
                rsum[r] += p;
                P[w][hi * 4 + r][n * 16 + lo] = f2bf(p);  // wave-private; lgkmcnt orders vs reads below
            }
        }
#pragma unroll
        for (int r = 0; r < 4; ++r) {
            float su = rsum[r];
            su += __shfl_xor(su, 1);
            su += __shfl_xor(su, 2);
            su += __shfl_xor(su, 4);
            su += __shfl_xor(su, 8);
            lsum[r] = lsum[r] * scl[r] + su;
        }
#pragma unroll
        for (int n = 0; n < 4; ++n)
#pragma unroll
            for (int r = 0; r < 4; ++r)
                o[n][r] *= scl[r];
        // PV: out(16q x 64d) += P(16 x 64) * V(64 x 64); B-operand = V^T rows (preloaded vf)
#pragma unroll
        for (int kk = 0; kk < 2; ++kk) {
            bf16x8 pf = *(const bf16x8*)&P[w][lo][kk * 32 + hi * 8];
#pragma unroll
            for (int n = 0; n < 4; ++n)
                o[n] = __builtin_amdgcn_mfma_f32_16x16x32_bf16(pf, vf[n][kk], o[n], 0, 0, 0);
        }
    }
    // epilogue: write bf16 attention output (b, s, h*64+d)
#pragma unroll
    for (int n = 0; n < 4; ++n) {
#pragma unroll
        for (int r = 0; r < 4; ++r) {
            int m = qr0 + hi * 4 + r;
            int d = n * 16 + lo;
            Ob[(size_t)(b * S_ + m) * DIM_ + h * 64 + d] = f2bf(o[n][r] / lsum[r]);
        }
    }
}

// ---------------- launch ----------------
extern "C" void kernel_launch(void* const* d_in, const int* in_sizes, int n_in,
                              void* d_out, int out_size, void* d_ws, size_t ws_size,
                              hipStream_t stream)
{
    const float* x  = (const float*)d_in[0];
    const float* cx = (const float*)d_in[1];
    const void* mask = d_in[2];
    const float* Wq = (const float*)d_in[3];
    const float* bq = (const float*)d_in[4];
    const float* Wk = (const float*)d_in[5];
    const float* bk = (const float*)d_in[6];
    const float* Wv = (const float*)d_in[7];
    const float* bv = (const float*)d_in[8];
    const float* Wo = (const float*)d_in[9];
    const float* bo = (const float*)d_in[10];

    unsigned short* ws = (unsigned short*)d_ws;
    const size_t XB  = 0;                                  // 8192*1024 (x bf16; later reused as attn out)
    const size_t CXB = XB  + (size_t)8192 * 1024;          // 4096*768
    const size_t WQT = CXB + (size_t)4096 * 768;           // 1024*1024
    const size_t WKT = WQT + (size_t)1024 * 1024;          // 1024*768
    const size_t WVT = WKT + (size_t)1024 * 768;           // 1024*768
    const size_t WOT = WVT + (size_t)1024 * 768;           // 1024*1024
    const size_t QB  = WOT + (size_t)1024 * 1024;          // 8192*1024
    const size_t KB  = QB  + (size_t)8192 * 1024;          // 4096*1024
    const size_t VTB = KB  + (size_t)4096 * 1024;          // 4*1024*1024
    const size_t FLG = VTB + (size_t)4 * 1024 * 1024;      // one int

    k_f32_to_bf16<<<2048, 256, 0, stream>>>(x,  ws + XB,  8192 * 1024 / 4);
    k_f32_to_bf16<<<2048, 256, 0, stream>>>(cx, ws + CXB, 4096 * 768 / 4);
    k_transposeW<<<1024, 256, 0, stream>>>(Wq, ws + WQT, 1024);
    k_transposeW<<<768,  256, 0, stream>>>(Wk, ws + WKT, 768);
    k_transposeW<<<768,  256, 0, stream>>>(Wv, ws + WVT, 768);
    k_transposeW<<<1024, 256, 0, stream>>>(Wo, ws + WOT, 1024);
    int* flag = (int*)(ws + FLG);
    k_mask_probe<<<1, 256, 0, stream>>>((const unsigned int*)mask, flag);

    dim3 gq(8192 / 128, 1024 / 128);
    dim3 gk(4096 / 128, 1024 / 128);
    k_gemm_bt<0><<<gq, 256, 0, stream>>>(ws + XB,  ws + WQT, bq, ws + QB, nullptr, 8192, 1024, 1024);
    k_gemm_bt<0><<<gk, 256, 0, stream>>>(ws + CXB, ws + WKT, bk, ws + KB, nullptr, 4096, 1024, 768);
    k_gemm_bt<1><<<gk, 256, 0, stream>>>(ws + CXB, ws + WVT, bv, ws + VTB, nullptr, 4096, 1024, 768);

    dim3 ga(S_ / 64, NH_, B_);
    k_attn<<<ga, 256, 0, stream>>>(ws + QB, ws + KB, ws + VTB, mask, flag, ws + XB);

    k_gemm_bt<2><<<gq, 256, 0, stream>>>(ws + XB, ws + WOT, bo, nullptr, (float*)d_out, 8192, 1024, 1024);
}